// Round 1
// baseline (1096.338 us; speedup 1.0000x reference)
//
#include <hip/hip_runtime.h>

#define B_   16
#define L_   190
#define DM_  512
#define DI_  1024
#define LB_  3040        // B_*L_

__device__ __forceinline__ float siluf(float v) { return v / (1.f + __expf(-v)); }
__device__ __forceinline__ float softplusf(float v) {
  return v > 0.f ? v + log1pf(__expf(-v)) : log1pf(__expf(v));
}

// ---------------------------------------------------------------------------
// pc_mask arrives as bool; on-wire dtype may be u8 / int32 / f32. All 190
// diagonal entries are True by construction (eye), so vote on the first 48
// (kept in-bounds under every hypothesis) and convert to f32.
__global__ __launch_bounds__(256) void mask_convert(const void* __restrict__ pcm,
                                                    float* __restrict__ maskf)
{
  __shared__ int votes[3];
  if (threadIdx.x < 3) votes[threadIdx.x] = 0;
  __syncthreads();
  if (threadIdx.x < 48) {
    int idx = threadIdx.x * 191;                       // (i, i) of a 190x190
    const unsigned char* p8  = (const unsigned char*)pcm;
    const unsigned int*  p32 = (const unsigned int*)pcm;
    if (p8[idx] == 1) atomicAdd(&votes[0], 1);
    unsigned int v = p32[idx];
    if (v == 1u)          atomicAdd(&votes[1], 1);
    if (v == 0x3f800000u) atomicAdd(&votes[2], 1);
  }
  __syncthreads();
  int mode = (votes[0] >= 48) ? 0 : (votes[1] >= 48 ? 1 : (votes[2] >= 48 ? 2 : 0));
  for (int i = threadIdx.x; i < L_ * L_; i += 256) {
    float v;
    if (mode == 0)      v = ((const unsigned char*)pcm)[i] ? 1.f : 0.f;
    else if (mode == 1) v = ((const int*)pcm)[i] ? 1.f : 0.f;
    else                v = ((const float*)pcm)[i];
    maskf[i] = v;
  }
}

// ---------------------------------------------------------------------------
// C[M,N] = epi( A[M,K](row stride lda) @ Bw[N,K]^T + bias )
// EPI: 0 none | 1 +bias | 2 (+bias)*aux[m,n] | 3 softplus(+bias) | 4 (+bias)*aux[m%L_, n]
template<int EPI>
__global__ __launch_bounds__(256) void gemm_epi(
    const float* __restrict__ A, int lda,
    const float* __restrict__ Bw,
    const float* __restrict__ bias,
    const float* __restrict__ aux,
    float* __restrict__ C,
    int M, int N, int K)
{
  __shared__ float As[16][65];
  __shared__ float Bs[16][65];
  const int tid = threadIdx.x;
  const int tx = tid & 15, ty = tid >> 4;
  const int lk = tid & 15;        // k within tile (contiguous per lane -> coalesced)
  const int lr = tid >> 4;        // base row
  const int m0 = blockIdx.y * 64, n0 = blockIdx.x * 64;
  float acc[4][4] = {};

  for (int k0 = 0; k0 < K; k0 += 16) {
    #pragma unroll
    for (int u = 0; u < 4; ++u) {
      int gk = k0 + lk;
      int gm = m0 + lr + 16 * u;
      As[lk][lr + 16 * u] = (gm < M && gk < K) ? A[(size_t)gm * lda + gk] : 0.f;
      int gn = n0 + lr + 16 * u;
      Bs[lk][lr + 16 * u] = (gn < N && gk < K) ? Bw[(size_t)gn * K + gk] : 0.f;
    }
    __syncthreads();
    #pragma unroll
    for (int k = 0; k < 16; ++k) {
      float a[4], b[4];
      #pragma unroll
      for (int i = 0; i < 4; ++i) a[i] = As[k][ty + 16 * i];
      #pragma unroll
      for (int j = 0; j < 4; ++j) b[j] = Bs[k][tx + 16 * j];
      #pragma unroll
      for (int i = 0; i < 4; ++i)
        #pragma unroll
        for (int j = 0; j < 4; ++j)
          acc[i][j] = fmaf(a[i], b[j], acc[i][j]);
    }
    __syncthreads();
  }

  #pragma unroll
  for (int i = 0; i < 4; ++i) {
    int gm = m0 + ty + 16 * i;
    if (gm >= M) continue;
    #pragma unroll
    for (int j = 0; j < 4; ++j) {
      int gn = n0 + tx + 16 * j;
      if (gn >= N) continue;
      float v = acc[i][j];
      if (EPI >= 1) v += bias[gn];
      if (EPI == 2) v *= aux[(size_t)gm * N + gn];
      if (EPI == 3) v = softplusf(v);
      if (EPI == 4) v *= aux[(size_t)(gm % L_) * N + gn];
      C[(size_t)gm * N + gn] = v;
    }
  }
}

// ---------------------------------------------------------------------------
// Depthwise conv(k=4) + bias + silu, both directions in one pass.
// fwd: causal (pad left 3). bwd: mamba(flip(h)) == anti-causal conv with
// flipped taps in original coordinates: sb[l] = sum_k w[k] * x[l+3-k].
__global__ __launch_bounds__(256) void conv_silu(
    const float* __restrict__ xz, const float* __restrict__ w,
    const float* __restrict__ cb,
    float* __restrict__ xcf, float* __restrict__ xcb)
{
  int idx = blockIdx.x * 256 + threadIdx.x;   // (b*L + l)*DI + c
  int c  = idx & (DI_ - 1);
  int bl = idx >> 10;
  int l = bl % L_;
  int b = bl / L_;
  float w0 = w[c * 4 + 0], w1 = w[c * 4 + 1], w2 = w[c * 4 + 2], w3 = w[c * 4 + 3];
  float bias = cb[c];
  const float* base = xz + (size_t)b * L_ * (2 * DI_) + c;   // xc = xz[..., :DI_]
  auto X = [&](int j) -> float { return (j >= 0 && j < L_) ? base[(size_t)j * (2 * DI_)] : 0.f; };
  float xm3 = X(l - 3), xm2 = X(l - 2), xm1 = X(l - 1), x0 = X(l);
  float xp1 = X(l + 1), xp2 = X(l + 2), xp3 = X(l + 3);
  float sf = fmaf(w0, xm3, fmaf(w1, xm2, fmaf(w2, xm1, fmaf(w3, x0, bias))));
  float sb = fmaf(w0, xp3, fmaf(w1, xp2, fmaf(w2, xp1, fmaf(w3, x0, bias))));
  xcf[idx] = siluf(sf);
  xcb[idx] = siluf(sb);
}

// ---------------------------------------------------------------------------
// Selective scan, one thread per (dir, b, d); 16 states in registers.
// dA, dBu computed on the fly; y = sum_s h_s * C_s + xc*D written IN PLACE
// over the dt buffer (each location read before written by the same thread).
__global__ __launch_bounds__(256) void scan_kernel(
    float* dtf, float* dtb,
    const float* __restrict__ xcf, const float* __restrict__ xcb,
    const float* __restrict__ xdf, const float* __restrict__ xdb,
    const float* __restrict__ A_log, const float* __restrict__ Dv)
{
  int tid = blockIdx.x * 256 + threadIdx.x;
  int d   = tid & (DI_ - 1);
  int b   = (tid >> 10) & (B_ - 1);
  int dir = tid >> 14;
  float* dty      = dir ? dtb : dtf;
  const float* xc = dir ? xcb : xcf;
  const float* xd = dir ? xdb : xdf;

  float A[16];
  #pragma unroll
  for (int s = 0; s < 16; ++s) A[s] = -__expf(A_log[d * 16 + s]);
  float Dd = Dv[d];
  float h[16];
  #pragma unroll
  for (int s = 0; s < 16; ++s) h[s] = 0.f;

  for (int step = 0; step < L_; ++step) {
    int l = dir ? (L_ - 1 - step) : step;
    size_t row = (size_t)b * L_ + l;
    float dtv = dty[row * DI_ + d];
    float xcv = xc[row * DI_ + d];
    float du  = dtv * xcv;
    const float* r = xd + row * 64;                  // x_dbl row: [dt(32) | B(16) | C(16)]
    float acc = 0.f;
    #pragma unroll
    for (int s = 0; s < 16; ++s) {
      float Bv = r[32 + s];
      float Cv = r[48 + s];
      h[s] = fmaf(__expf(dtv * A[s]), h[s], du * Bv);
      acc  = fmaf(h[s], Cv, acc);
    }
    dty[row * DI_ + d] = fmaf(xcv, Dd, acc);
  }
}

// yz = (y_f + y_b) * silu(z), z = xz[..., DI_:]
__global__ __launch_bounds__(256) void combine_yz(
    const float* __restrict__ yf, const float* __restrict__ yb,
    const float* __restrict__ xz, float* __restrict__ yz)
{
  int idx = blockIdx.x * 256 + threadIdx.x;
  int c = idx & (DI_ - 1);
  int rowi = idx >> 10;
  float z = xz[(size_t)rowi * (2 * DI_) + DI_ + c];
  yz[idx] = (yf[idx] + yb[idx]) * siluf(z);
}

// ---------------------------------------------------------------------------
// tanh-LayerNorm over (L, D) per batch, two kernels for parallelism.
__global__ __launch_bounds__(256) void ln_partial(const float* __restrict__ x,
                                                  float* __restrict__ partials)
{
  int b = blockIdx.y, ch = blockIdx.x;               // 8 chunks of 12160
  const float* xb = x + (size_t)b * (L_ * DM_);
  int lo = ch * 12160, hi = lo + 12160;
  float s = 0.f, s2 = 0.f;
  for (int i = lo + threadIdx.x; i < hi; i += 256) {
    float t = tanhf(xb[i]);
    s += t; s2 = fmaf(t, t, s2);
  }
  #pragma unroll
  for (int off = 32; off > 0; off >>= 1) { s += __shfl_down(s, off); s2 += __shfl_down(s2, off); }
  __shared__ float rs[4], rs2[4];
  int wid = threadIdx.x >> 6, lane = threadIdx.x & 63;
  if (lane == 0) { rs[wid] = s; rs2[wid] = s2; }
  __syncthreads();
  if (threadIdx.x == 0) {
    partials[(b * 8 + ch) * 2 + 0] = rs[0] + rs[1] + rs[2] + rs[3];
    partials[(b * 8 + ch) * 2 + 1] = rs2[0] + rs2[1] + rs2[2] + rs2[3];
  }
}

__global__ __launch_bounds__(256) void ln_final(const float* __restrict__ x,
    const float* __restrict__ partials,
    const float* __restrict__ nw, const float* __restrict__ nb,
    float* __restrict__ out)
{
  int b = blockIdx.y, ch = blockIdx.x;
  float S = 0.f, S2 = 0.f;
  #pragma unroll
  for (int i = 0; i < 8; ++i) { S += partials[(b * 8 + i) * 2 + 0]; S2 += partials[(b * 8 + i) * 2 + 1]; }
  const float inv = 1.f / (float)(L_ * DM_);
  float mu = S * inv;
  float var = S2 * inv - mu * mu;
  float r = rsqrtf(var + 1e-5f);
  const float* xb = x + (size_t)b * (L_ * DM_);
  float* ob = out + (size_t)b * (L_ * DM_);
  int lo = ch * 12160, hi = lo + 12160;
  for (int i = lo + threadIdx.x; i < hi; i += 256) {
    float t = tanhf(xb[i]);
    ob[i] = fmaf((t - mu) * r, nw[i], nb[i]);
  }
}

// ---------------------------------------------------------------------------
extern "C" void kernel_launch(void* const* d_in, const int* in_sizes, int n_in,
                              void* d_out, int out_size, void* d_ws, size_t ws_size,
                              hipStream_t stream)
{
  const float* x            = (const float*)d_in[0];
  const void*  pc_mask      = d_in[1];
  const float* in_resize_w  = (const float*)d_in[2];
  const float* in_resize_b  = (const float*)d_in[3];
  const float* in_reset_w   = (const float*)d_in[4];
  const float* in_reset_b   = (const float*)d_in[5];
  const float* out_resize_w = (const float*)d_in[6];
  const float* out_resize_b = (const float*)d_in[7];
  const float* out_reset_w  = (const float*)d_in[8];
  const float* out_reset_b  = (const float*)d_in[9];
  const float* in_proj_w    = (const float*)d_in[10];
  const float* conv_w       = (const float*)d_in[11];
  const float* conv_b       = (const float*)d_in[12];
  const float* x_proj_w     = (const float*)d_in[13];
  const float* dt_proj_w    = (const float*)d_in[14];
  const float* dt_proj_b    = (const float*)d_in[15];
  const float* A_log        = (const float*)d_in[16];
  const float* Dv           = (const float*)d_in[17];
  const float* out_proj_w   = (const float*)d_in[18];
  const float* norm_w       = (const float*)d_in[19];
  const float* norm_b       = (const float*)d_in[20];

  float* W = (float*)d_ws;                  // ~85.2 MB of f32 scratch
  float* maskf    = W + 0;                  //    36,100
  float* h1       = W + 40000;              //   577,600  (reused as o2)
  float* h        = W + 620000;             // 1,556,480  (reused as o_pre)
  float* xz       = W + 2180000;            // 6,225,920
  float* xcf      = W + 8410000;            // 3,112,960  (reused as yz)
  float* xcb      = W + 11530000;           // 3,112,960
  float* xdf      = W + 14650000;           //   194,560
  float* xdb      = W + 14850000;           //   194,560
  float* dtf      = W + 15050000;           // 3,112,960  (reused as y_f)
  float* dtb      = W + 18170000;           // 3,112,960  (reused as y_b)
  float* partials = W + 21290000;           //       256

  float* out_ln = (float*)d_out;                        // output 0: layernorm(tanh(x))
  float* out_o  = (float*)d_out + (size_t)LB_ * DM_;    // output 1: mamba path

  dim3 blk(256);
  auto grid2 = [](int M, int N) { return dim3((unsigned)((N + 63) / 64), (unsigned)((M + 63) / 64)); };

  mask_convert<<<1, 256, 0, stream>>>(pc_mask, maskf);

  // h1 = x @ in_resize_w^T + b          (* m[0,0] == 1 by construction: diag of eye-mask)
  gemm_epi<1><<<grid2(LB_, L_), blk, 0, stream>>>(x, DM_, in_resize_w, in_resize_b, nullptr, h1, LB_, L_, DM_);
  // h  = (h1 @ in_reset_w^T + b) * x
  gemm_epi<2><<<grid2(LB_, DM_), blk, 0, stream>>>(h1, L_, in_reset_w, in_reset_b, x, h, LB_, DM_, L_);
  // xz = h @ in_proj_w^T                (shared by both directions: flip commutes)
  gemm_epi<0><<<grid2(LB_, 2 * DI_), blk, 0, stream>>>(h, DM_, in_proj_w, nullptr, nullptr, xz, LB_, 2 * DI_, DM_);
  // depthwise conv + silu, both directions
  conv_silu<<<(LB_ * DI_) / 256, blk, 0, stream>>>(xz, conv_w, conv_b, xcf, xcb);
  // x_dbl = xc @ x_proj_w^T  (per direction)
  gemm_epi<0><<<grid2(LB_, 64), blk, 0, stream>>>(xcf, DI_, x_proj_w, nullptr, nullptr, xdf, LB_, 64, DI_);
  gemm_epi<0><<<grid2(LB_, 64), blk, 0, stream>>>(xcb, DI_, x_proj_w, nullptr, nullptr, xdb, LB_, 64, DI_);
  // dt = softplus(x_dbl[:, :32] @ dt_proj_w^T + b)
  gemm_epi<3><<<grid2(LB_, DI_), blk, 0, stream>>>(xdf, 64, dt_proj_w, dt_proj_b, nullptr, dtf, LB_, DI_, 32);
  gemm_epi<3><<<grid2(LB_, DI_), blk, 0, stream>>>(xdb, 64, dt_proj_w, dt_proj_b, nullptr, dtb, LB_, DI_, 32);
  // selective scan (both directions), y written in place over dt
  scan_kernel<<<(2 * B_ * DI_) / 256, blk, 0, stream>>>(dtf, dtb, xcf, xcb, xdf, xdb, A_log, Dv);
  // yz = (y_f + y_b) * silu(z)   -> enables single fused out_proj GEMM
  combine_yz<<<(LB_ * DI_) / 256, blk, 0, stream>>>(dtf, dtb, xz, xcf);
  // o_pre = yz @ out_proj_w^T
  gemm_epi<0><<<grid2(LB_, DM_), blk, 0, stream>>>(xcf, DI_, out_proj_w, nullptr, nullptr, h, LB_, DM_, DI_);
  // o2 = (o_pre @ out_resize_w^T + b) * mask[l, :]
  gemm_epi<4><<<grid2(LB_, L_), blk, 0, stream>>>(h, DM_, out_resize_w, out_resize_b, maskf, h1, LB_, L_, DM_);
  // o  = (o2 @ out_reset_w^T + b) * x   -> output 1
  gemm_epi<2><<<grid2(LB_, DM_), blk, 0, stream>>>(h1, L_, out_reset_w, out_reset_b, x, out_o, LB_, DM_, L_);
  // output 0: layernorm(tanh(x)) per batch
  dim3 lgrid(8, B_);
  ln_partial<<<lgrid, blk, 0, stream>>>(x, partials);
  ln_final<<<lgrid, blk, 0, stream>>>(x, partials, norm_w, norm_b, out_ln);
}

// Round 2
// 517.901 us; speedup vs baseline: 2.1169x; 2.1169x over previous
//
#include <hip/hip_runtime.h>
#include <hip/hip_bf16.h>

#define B_    16
#define L_    190
#define LP_   192        // padded L
#define DM_   512
#define DI_   1024
#define LB_   3040       // B_*L_
#define LBDI_ 3112960    // LB_*DI_

typedef __attribute__((ext_vector_type(8))) short bf16x8;
typedef __attribute__((ext_vector_type(4))) float f32x4;

typedef const __attribute__((address_space(1))) void gvoid;
typedef __attribute__((address_space(3))) void lvoid;
#define LOAD_LDS16(g, l) __builtin_amdgcn_global_load_lds((gvoid*)(g), (lvoid*)(l), 16, 0, 0)

__device__ __forceinline__ float siluf(float v) { return v / (1.f + __expf(-v)); }
__device__ __forceinline__ float softplusf(float v) {
  return v > 0.f ? v + log1pf(__expf(-v)) : log1pf(__expf(v));
}

// ---------------------------------------------------------------------------
// pc_mask dtype vote (u8 / i32 / f32) -> f32 [190][192], cols 190-191 zero.
__global__ __launch_bounds__(256) void mask_convert(const void* __restrict__ pcm,
                                                    float* __restrict__ maskf)
{
  __shared__ int votes[3];
  if (threadIdx.x < 3) votes[threadIdx.x] = 0;
  __syncthreads();
  if (threadIdx.x < 48) {
    int idx = threadIdx.x * 191;
    const unsigned char* p8  = (const unsigned char*)pcm;
    const unsigned int*  p32 = (const unsigned int*)pcm;
    if (p8[idx] == 1) atomicAdd(&votes[0], 1);
    unsigned int v = p32[idx];
    if (v == 1u)          atomicAdd(&votes[1], 1);
    if (v == 0x3f800000u) atomicAdd(&votes[2], 1);
  }
  __syncthreads();
  int mode = (votes[0] >= 48) ? 0 : (votes[1] >= 48 ? 1 : (votes[2] >= 48 ? 2 : 0));
  for (int i = threadIdx.x; i < L_ * LP_; i += 256) {
    int r = i / LP_, c = i % LP_;
    float v = 0.f;
    if (c < L_) {
      int s = r * L_ + c;
      if (mode == 0)      v = ((const unsigned char*)pcm)[s] ? 1.f : 0.f;
      else if (mode == 1) v = ((const int*)pcm)[s] ? 1.f : 0.f;
      else                v = ((const float*)pcm)[s];
    }
    maskf[i] = v;
  }
}

// f32 [R,C] -> bf16 [Rp,Cp] zero-padded
__global__ __launch_bounds__(256) void cvt_pad_bf(const float* __restrict__ src,
                                                  __hip_bfloat16* __restrict__ dst,
                                                  int R, int C, int Rp, int Cp)
{
  int tot = Rp * Cp;
  for (int i = blockIdx.x * 256 + threadIdx.x; i < tot; i += gridDim.x * 256) {
    int r = i / Cp, c = i % Cp;
    float v = (r < R && c < C) ? src[(size_t)r * C + c] : 0.f;
    dst[i] = __float2bfloat16(v);
  }
}

__global__ __launch_bounds__(256) void pad_bias(const float* __restrict__ src,
                                                float* __restrict__ dst, int n, int np)
{
  int i = threadIdx.x;
  if (i < np) dst[i] = (i < n) ? src[i] : 0.f;
}

// ---------------------------------------------------------------------------
// MFMA GEMM: C[M,N] = epi( A_bf16[M,K](row-stride lda) @ W_bf16[N,K]^T )
// 128x128 block, 4 waves (2x2) x 64x64/wave, 4x4 frags of 16x16x32, K%32==0.
// EPI: 0 none | 1 +bias | 2 (+bias)*aux[m*N+n] | 3 softplus(+bias) | 4 (+bias)*aux[(m%190)*N+n]
template<int EPI, bool OF32, bool OBF>
__global__ __launch_bounds__(256) void gemm_mfma(
    const __hip_bfloat16* __restrict__ A, int lda, int M,
    const __hip_bfloat16* __restrict__ Bw, int Brows,
    const float* __restrict__ bias, const float* __restrict__ aux,
    float* __restrict__ Cf, __hip_bfloat16* __restrict__ Cb,
    int N, int K)
{
  __shared__ bf16x8 SA[2][512];
  __shared__ bf16x8 SB[2][512];
  const int tid = threadIdx.x;
  const int wave = tid >> 6, lane = tid & 63;
  const int m0 = blockIdx.y * 128, n0 = blockIdx.x * 128;
  const int wm = (wave >> 1) * 64, wn = (wave & 1) * 64;
  const int l15 = lane & 15, lkb = lane >> 4;

  f32x4 acc[4][4] = {};

  auto stage = [&](int bsel, int k0) {
    #pragma unroll
    for (int it = 0; it < 2; ++it) {
      int c = it * 256 + tid;
      int row = c & 127, kb = c >> 7;
      int ar = m0 + row; ar = ar < M ? ar : M - 1;
      const __hip_bfloat16* ga = A + (size_t)ar * lda + (k0 + kb * 8);
      LOAD_LDS16(ga, &SA[bsel][it * 256 + wave * 64]);
      int br = n0 + row; br = br < Brows ? br : Brows - 1;
      const __hip_bfloat16* gb = Bw + (size_t)br * K + (k0 + kb * 8);
      LOAD_LDS16(gb, &SB[bsel][it * 256 + wave * 64]);
    }
  };

  const int nk = K >> 5;
  stage(0, 0);
  __syncthreads();
  int buf = 0;
  for (int kt = 0; kt < nk; ++kt) {
    if (kt + 1 < nk) stage(buf ^ 1, (kt + 1) * 32);
    bf16x8 af[4], bq[4];
    #pragma unroll
    for (int f = 0; f < 4; ++f) {
      af[f] = SA[buf][lkb * 128 + wm + f * 16 + l15];
      bq[f] = SB[buf][lkb * 128 + wn + f * 16 + l15];
    }
    #pragma unroll
    for (int i = 0; i < 4; ++i)
      #pragma unroll
      for (int j = 0; j < 4; ++j)
        acc[i][j] = __builtin_amdgcn_mfma_f32_16x16x32_bf16(af[i], bq[j], acc[i][j], 0, 0, 0);
    __syncthreads();
    buf ^= 1;
  }

  // C/D layout: col = lane&15, row = (lane>>4)*4 + reg
  #pragma unroll
  for (int i = 0; i < 4; ++i) {
    int r0 = m0 + wm + i * 16 + (lkb << 2);
    #pragma unroll
    for (int j = 0; j < 4; ++j) {
      int col = n0 + wn + j * 16 + l15;
      if (col >= N) continue;
      #pragma unroll
      for (int r = 0; r < 4; ++r) {
        int row = r0 + r;
        if (row >= M) continue;
        float v = acc[i][j][r];
        if (EPI >= 1) v += bias[col];
        if (EPI == 2) v *= aux[(size_t)row * N + col];
        if (EPI == 3) v = softplusf(v);
        if (EPI == 4) v *= aux[(size_t)(row % L_) * N + col];
        if (OF32) Cf[(size_t)row * N + col] = v;
        if (OBF)  Cb[(size_t)row * N + col] = __float2bfloat16(v);
      }
    }
  }
}

// ---------------------------------------------------------------------------
// Depthwise conv(k=4) + bias + silu, both directions; bf16 in (xz), bf16 out.
__global__ __launch_bounds__(256) void conv_silu(
    const __hip_bfloat16* __restrict__ xz, const float* __restrict__ w,
    const float* __restrict__ cb, __hip_bfloat16* __restrict__ xcbf)
{
  int idx = blockIdx.x * 256 + threadIdx.x;   // (b*L + l)*DI + c
  int c  = idx & (DI_ - 1);
  int bl = idx >> 10;
  int l = bl % L_;
  int b = bl / L_;
  float w0 = w[c * 4 + 0], w1 = w[c * 4 + 1], w2 = w[c * 4 + 2], w3 = w[c * 4 + 3];
  float bias = cb[c];
  const __hip_bfloat16* base = xz + (size_t)b * L_ * (2 * DI_) + c;
  auto X = [&](int j) -> float {
    return (j >= 0 && j < L_) ? __bfloat162float(base[(size_t)j * (2 * DI_)]) : 0.f;
  };
  float xm3 = X(l - 3), xm2 = X(l - 2), xm1 = X(l - 1), x0 = X(l);
  float xp1 = X(l + 1), xp2 = X(l + 2), xp3 = X(l + 3);
  float sf = fmaf(w0, xm3, fmaf(w1, xm2, fmaf(w2, xm1, fmaf(w3, x0, bias))));
  float sb = fmaf(w0, xp3, fmaf(w1, xp2, fmaf(w2, xp1, fmaf(w3, x0, bias))));
  xcbf[idx]          = __float2bfloat16(siluf(sf));
  xcbf[LBDI_ + idx]  = __float2bfloat16(siluf(sb));
}

// ---------------------------------------------------------------------------
// Selective scan, one thread per (dir,b,d); y overwrites dt in place.
__global__ __launch_bounds__(256) void scan_kernel(
    float* __restrict__ dt, const __hip_bfloat16* __restrict__ xcbf,
    const float* __restrict__ xd,
    const float* __restrict__ A_log, const float* __restrict__ Dv)
{
  int tid = blockIdx.x * 256 + threadIdx.x;
  int d   = tid & (DI_ - 1);
  int b   = (tid >> 10) & (B_ - 1);
  int dir = tid >> 14;
  float* dty = dt + (size_t)dir * LBDI_;
  const __hip_bfloat16* xc = xcbf + (size_t)dir * LBDI_;
  const float* xdp = xd + (size_t)dir * LB_ * 64;

  float A[16];
  #pragma unroll
  for (int s = 0; s < 16; ++s) A[s] = -__expf(A_log[d * 16 + s]);
  float Dd = Dv[d];
  float h[16];
  #pragma unroll
  for (int s = 0; s < 16; ++s) h[s] = 0.f;

  for (int step = 0; step < L_; ++step) {
    int l = dir ? (L_ - 1 - step) : step;
    size_t row = (size_t)b * L_ + l;
    float dtv = dty[row * DI_ + d];
    float xcv = __bfloat162float(xc[row * DI_ + d]);
    float du  = dtv * xcv;
    const float* r = xdp + row * 64;   // [dt(32) | B(16) | C(16)]
    float acc = 0.f;
    #pragma unroll
    for (int s = 0; s < 16; ++s) {
      float Bv = r[32 + s];
      float Cv = r[48 + s];
      h[s] = fmaf(__expf(dtv * A[s]), h[s], du * Bv);
      acc  = fmaf(h[s], Cv, acc);
    }
    dty[row * DI_ + d] = fmaf(xcv, Dd, acc);
  }
}

// yz = (y_f + y_b) * silu(z) -> bf16
__global__ __launch_bounds__(256) void combine_yz(
    const float* __restrict__ y, const __hip_bfloat16* __restrict__ xz,
    __hip_bfloat16* __restrict__ yz)
{
  int idx = blockIdx.x * 256 + threadIdx.x;
  int c = idx & (DI_ - 1);
  int rowi = idx >> 10;
  float z = __bfloat162float(xz[(size_t)rowi * (2 * DI_) + DI_ + c]);
  float v = (y[idx] + y[LBDI_ + idx]) * siluf(z);
  yz[idx] = __float2bfloat16(v);
}

// ---------------------------------------------------------------------------
// tanh-LayerNorm over (L, D) per batch.
__global__ __launch_bounds__(256) void ln_partial(const float* __restrict__ x,
                                                  float* __restrict__ partials)
{
  int b = blockIdx.y, ch = blockIdx.x;
  const float* xb = x + (size_t)b * (L_ * DM_);
  int lo = ch * 12160, hi = lo + 12160;
  float s = 0.f, s2 = 0.f;
  for (int i = lo + threadIdx.x; i < hi; i += 256) {
    float t = tanhf(xb[i]);
    s += t; s2 = fmaf(t, t, s2);
  }
  #pragma unroll
  for (int off = 32; off > 0; off >>= 1) { s += __shfl_down(s, off); s2 += __shfl_down(s2, off); }
  __shared__ float rs[4], rs2[4];
  int wid = threadIdx.x >> 6, lane = threadIdx.x & 63;
  if (lane == 0) { rs[wid] = s; rs2[wid] = s2; }
  __syncthreads();
  if (threadIdx.x == 0) {
    partials[(b * 8 + ch) * 2 + 0] = rs[0] + rs[1] + rs[2] + rs[3];
    partials[(b * 8 + ch) * 2 + 1] = rs2[0] + rs2[1] + rs2[2] + rs2[3];
  }
}

__global__ __launch_bounds__(256) void ln_final(const float* __restrict__ x,
    const float* __restrict__ partials,
    const float* __restrict__ nw, const float* __restrict__ nb,
    float* __restrict__ out)
{
  int b = blockIdx.y, ch = blockIdx.x;
  float S = 0.f, S2 = 0.f;
  #pragma unroll
  for (int i = 0; i < 8; ++i) { S += partials[(b * 8 + i) * 2 + 0]; S2 += partials[(b * 8 + i) * 2 + 1]; }
  const float inv = 1.f / (float)(L_ * DM_);
  float mu = S * inv;
  float var = S2 * inv - mu * mu;
  float r = rsqrtf(var + 1e-5f);
  const float* xb = x + (size_t)b * (L_ * DM_);
  float* ob = out + (size_t)b * (L_ * DM_);
  int lo = ch * 12160, hi = lo + 12160;
  for (int i = lo + threadIdx.x; i < hi; i += 256) {
    float t = tanhf(xb[i]);
    ob[i] = fmaf((t - mu) * r, nw[i], nb[i]);
  }
}

// ---------------------------------------------------------------------------
extern "C" void kernel_launch(void* const* d_in, const int* in_sizes, int n_in,
                              void* d_out, int out_size, void* d_ws, size_t ws_size,
                              hipStream_t stream)
{
  const float* x            = (const float*)d_in[0];
  const void*  pc_mask      = d_in[1];
  const float* in_resize_w  = (const float*)d_in[2];
  const float* in_resize_b  = (const float*)d_in[3];
  const float* in_reset_w   = (const float*)d_in[4];
  const float* in_reset_b   = (const float*)d_in[5];
  const float* out_resize_w = (const float*)d_in[6];
  const float* out_resize_b = (const float*)d_in[7];
  const float* out_reset_w  = (const float*)d_in[8];
  const float* out_reset_b  = (const float*)d_in[9];
  const float* in_proj_w    = (const float*)d_in[10];
  const float* conv_w       = (const float*)d_in[11];
  const float* conv_b       = (const float*)d_in[12];
  const float* x_proj_w     = (const float*)d_in[13];
  const float* dt_proj_w    = (const float*)d_in[14];
  const float* dt_proj_b    = (const float*)d_in[15];
  const float* A_log        = (const float*)d_in[16];
  const float* Dv           = (const float*)d_in[17];
  const float* out_proj_w   = (const float*)d_in[18];
  const float* norm_w       = (const float*)d_in[19];
  const float* norm_b       = (const float*)d_in[20];

  // ---- workspace layout (f32 region then bf16 region) ----
  float* W = (float*)d_ws;
  float* maskf    = W + 0;         // 190*192 = 36480
  float* b_inrs   = W + 36480;     // 192
  float* b_outrs  = W + 36672;     // 192
  float* xd       = W + 36864;     // 2*3040*64 = 389120
  float* dt       = W + 425984;    // 2*3040*1024 = 6225920
  float* partials = W + 6651904;   // 256
  __hip_bfloat16* BF = (__hip_bfloat16*)(W + 6652160);
  __hip_bfloat16* w_inrs  = BF + 0;         // 192*512
  __hip_bfloat16* w_inrt  = BF + 98304;     // 512*192
  __hip_bfloat16* w_inpj  = BF + 196608;    // 2048*512
  __hip_bfloat16* w_xpj   = BF + 1245184;   // 64*1024
  __hip_bfloat16* w_dtpj  = BF + 1310720;   // 1024*32
  __hip_bfloat16* w_outpj = BF + 1343488;   // 512*1024
  __hip_bfloat16* w_outrs = BF + 1867776;   // 192*512
  __hip_bfloat16* w_outrt = BF + 1966080;   // 512*192
  __hip_bfloat16* x_bf    = BF + 2064384;   // 3040*512
  __hip_bfloat16* h1_bf   = BF + 3620864;   // 3040*192
  __hip_bfloat16* h_bf    = BF + 4204544;   // 3040*512
  __hip_bfloat16* xz_bf   = BF + 5761024;   // 3040*2048
  __hip_bfloat16* xc_bf   = BF + 11986944;  // 2*3040*1024
  __hip_bfloat16* xd_bf   = BF + 18212864;  // 2*3040*64
  __hip_bfloat16* yz_bf   = BF + 18601984;  // 3040*1024
  __hip_bfloat16* o_pre   = BF + 21714944;  // 3040*512
  __hip_bfloat16* o2_bf   = BF + 23271424;  // 3040*192
  // total bf16 = 23,855,104 elems; ws usage ~74.3 MB

  float* out_ln = (float*)d_out;
  float* out_o  = (float*)d_out + (size_t)LB_ * DM_;

  dim3 blk(256);
  auto cg = [](int tot) { return dim3((unsigned)((tot + 255) / 256 > 2048 ? 2048 : (tot + 255) / 256)); };

  // conversions (all independent)
  mask_convert<<<1, blk, 0, stream>>>(pc_mask, maskf);
  pad_bias<<<1, blk, 0, stream>>>(in_resize_b,  b_inrs,  L_, LP_);
  pad_bias<<<1, blk, 0, stream>>>(out_resize_b, b_outrs, L_, LP_);
  cvt_pad_bf<<<cg(3040*512),  blk, 0, stream>>>(x,            x_bf,    3040, 512, 3040, 512);
  cvt_pad_bf<<<cg(192*512),   blk, 0, stream>>>(in_resize_w,  w_inrs,  190, 512, 192, 512);
  cvt_pad_bf<<<cg(512*192),   blk, 0, stream>>>(in_reset_w,   w_inrt,  512, 190, 512, 192);
  cvt_pad_bf<<<cg(2048*512),  blk, 0, stream>>>(in_proj_w,    w_inpj,  2048, 512, 2048, 512);
  cvt_pad_bf<<<cg(64*1024),   blk, 0, stream>>>(x_proj_w,     w_xpj,   64, 1024, 64, 1024);
  cvt_pad_bf<<<cg(1024*32),   blk, 0, stream>>>(dt_proj_w,    w_dtpj,  1024, 32, 1024, 32);
  cvt_pad_bf<<<cg(512*1024),  blk, 0, stream>>>(out_proj_w,   w_outpj, 512, 1024, 512, 1024);
  cvt_pad_bf<<<cg(192*512),   blk, 0, stream>>>(out_resize_w, w_outrs, 190, 512, 192, 512);
  cvt_pad_bf<<<cg(512*192),   blk, 0, stream>>>(out_reset_w,  w_outrt, 512, 190, 512, 192);

  // h1 = x @ in_resize_w^T + b                       (m[0,0]==1: diag of eye)
  gemm_mfma<1,false,true><<<dim3(2,24), blk, 0, stream>>>(x_bf, 512, 3040, w_inrs, 192, b_inrs, nullptr, nullptr, h1_bf, LP_, 512);
  // h = (h1 @ in_reset_w^T + b) * x
  gemm_mfma<2,false,true><<<dim3(4,24), blk, 0, stream>>>(h1_bf, LP_, 3040, w_inrt, 512, in_reset_b, x, nullptr, h_bf, 512, LP_);
  // xz = h @ in_proj_w^T
  gemm_mfma<0,false,true><<<dim3(16,24), blk, 0, stream>>>(h_bf, 512, 3040, w_inpj, 2048, nullptr, nullptr, nullptr, xz_bf, 2048, 512);
  // conv + silu (both dirs)
  conv_silu<<<dim3(LBDI_/256), blk, 0, stream>>>(xz_bf, conv_w, conv_b, xc_bf);
  // x_dbl = xc @ x_proj_w^T  (both dirs batched: M=6080)
  gemm_mfma<0,true,true><<<dim3(1,48), blk, 0, stream>>>(xc_bf, 1024, 6080, w_xpj, 64, nullptr, nullptr, xd, xd_bf, 64, 1024);
  // dt = softplus(x_dbl[:,:32] @ dt_proj_w^T + b)    (M=6080, K=32)
  gemm_mfma<3,true,false><<<dim3(8,48), blk, 0, stream>>>(xd_bf, 64, 6080, w_dtpj, 1024, dt_proj_b, nullptr, dt, nullptr, 1024, 32);
  // selective scan (y in place over dt)
  scan_kernel<<<dim3(2*B_*DI_/256), blk, 0, stream>>>(dt, xc_bf, xd, A_log, Dv);
  // yz = (y_f + y_b) * silu(z)
  combine_yz<<<dim3(LBDI_/256), blk, 0, stream>>>(dt, xz_bf, yz_bf);
  // o_pre = yz @ out_proj_w^T
  gemm_mfma<0,false,true><<<dim3(4,24), blk, 0, stream>>>(yz_bf, 1024, 3040, w_outpj, 512, nullptr, nullptr, nullptr, o_pre, 512, 1024);
  // o2 = (o_pre @ out_resize_w^T + b) * mask[l,:]
  gemm_mfma<4,false,true><<<dim3(2,24), blk, 0, stream>>>(o_pre, 512, 3040, w_outrs, 192, b_outrs, maskf, nullptr, o2_bf, LP_, 512);
  // o = (o2 @ out_reset_w^T + b) * x  -> output 1
  gemm_mfma<2,true,false><<<dim3(4,24), blk, 0, stream>>>(o2_bf, LP_, 3040, w_outrt, 512, out_reset_b, x, out_o, nullptr, 512, LP_);
  // output 0: layernorm(tanh(x))
  dim3 lgrid(8, B_);
  ln_partial<<<lgrid, blk, 0, stream>>>(x, partials);
  ln_final<<<lgrid, blk, 0, stream>>>(x, partials, norm_w, norm_b, out_ln);
}

// Round 3
// 452.331 us; speedup vs baseline: 2.4238x; 1.1450x over previous
//
#include <hip/hip_runtime.h>
#include <hip/hip_bf16.h>

#define B_    16
#define L_    190
#define LP_   192        // padded L
#define DM_   512
#define DI_   1024
#define LB_   3040       // B_*L_
#define LBDI_ 3112960    // LB_*DI_

typedef __attribute__((ext_vector_type(8))) short bf16x8;
typedef __attribute__((ext_vector_type(4))) float f32x4;
typedef __attribute__((ext_vector_type(4))) unsigned short u16x4;

typedef const __attribute__((address_space(1))) void gvoid;
typedef __attribute__((address_space(3))) void lvoid;
#define LOAD_LDS16(g, l) __builtin_amdgcn_global_load_lds((gvoid*)(g), (lvoid*)(l), 16, 0, 0)

__device__ __forceinline__ float siluf(float v) { return v / (1.f + __expf(-v)); }
__device__ __forceinline__ float softplusf(float v) {
  return v > 0.f ? v + log1pf(__expf(-v)) : log1pf(__expf(v));
}

// ---------------------------------------------------------------------------
// pc_mask dtype vote (u8 / i32 / f32) -> f32 [190][192]; also pads 2 biases.
__global__ __launch_bounds__(256) void mask_convert(const void* __restrict__ pcm,
                                                    float* __restrict__ maskf,
                                                    const float* __restrict__ irb,
                                                    const float* __restrict__ orb,
                                                    float* __restrict__ b_inrs,
                                                    float* __restrict__ b_outrs)
{
  __shared__ int votes[3];
  if (threadIdx.x < 3) votes[threadIdx.x] = 0;
  __syncthreads();
  if (threadIdx.x < 48) {
    int idx = threadIdx.x * 191;
    const unsigned char* p8  = (const unsigned char*)pcm;
    const unsigned int*  p32 = (const unsigned int*)pcm;
    if (p8[idx] == 1) atomicAdd(&votes[0], 1);
    unsigned int v = p32[idx];
    if (v == 1u)          atomicAdd(&votes[1], 1);
    if (v == 0x3f800000u) atomicAdd(&votes[2], 1);
  }
  __syncthreads();
  int mode = (votes[0] >= 48) ? 0 : (votes[1] >= 48 ? 1 : (votes[2] >= 48 ? 2 : 0));
  for (int i = threadIdx.x; i < L_ * LP_; i += 256) {
    int r = i / LP_, c = i % LP_;
    float v = 0.f;
    if (c < L_) {
      int s = r * L_ + c;
      if (mode == 0)      v = ((const unsigned char*)pcm)[s] ? 1.f : 0.f;
      else if (mode == 1) v = ((const int*)pcm)[s] ? 1.f : 0.f;
      else                v = ((const float*)pcm)[s];
    }
    maskf[i] = v;
  }
  if (threadIdx.x < LP_) {
    b_inrs[threadIdx.x]  = (threadIdx.x < L_) ? irb[threadIdx.x] : 0.f;
    b_outrs[threadIdx.x] = (threadIdx.x < L_) ? orb[threadIdx.x] : 0.f;
  }
}

// ---------------------------------------------------------------------------
// One kernel converting all f32 tensors -> padded bf16 (9 segments).
struct CvtDesc { const float* src; __hip_bfloat16* dst; int R, C, Rp, Cp, end; };
struct CvtPack { CvtDesc d[9]; int total; };

__global__ __launch_bounds__(256) void cvt_all(CvtPack p)
{
  for (int i = blockIdx.x * 256 + threadIdx.x; i < p.total; i += gridDim.x * 256) {
    int seg = 0;
    #pragma unroll
    for (int s = 0; s < 9; ++s) if (i >= p.d[s].end - (p.d[s].Rp * p.d[s].Cp)) seg = s; else break;
    const CvtDesc& D = p.d[seg];
    int local = i - (D.end - D.Rp * D.Cp);
    int r = local / D.Cp, c = local % D.Cp;
    float v = (r < D.R && c < D.C) ? D.src[(size_t)r * D.C + c] : 0.f;
    D.dst[local] = __float2bfloat16(v);
  }
}

// ---------------------------------------------------------------------------
// MFMA GEMM: C[M,N] = epi( A_bf16[M,K](row-stride lda) @ W_bf16[N,K]^T )
// 128x128 block, 4 waves (2x2) x 64x64/wave, 4x4 frags of 16x16x32, K%32==0.
// EPI: 0 none | 1 +bias | 2 (+bias)*aux[m*N+n] | 3 softplus(+bias) | 4 (+bias)*aux[(m%190)*N+n]
template<int EPI, bool OF32, bool OBF>
__global__ __launch_bounds__(256) void gemm_mfma(
    const __hip_bfloat16* __restrict__ A, int lda, int M,
    const __hip_bfloat16* __restrict__ Bw, int Brows,
    const float* __restrict__ bias, const float* __restrict__ aux,
    float* __restrict__ Cf, __hip_bfloat16* __restrict__ Cb,
    int N, int K)
{
  __shared__ bf16x8 SA[2][512];
  __shared__ bf16x8 SB[2][512];
  const int tid = threadIdx.x;
  const int wave = tid >> 6, lane = tid & 63;
  const int m0 = blockIdx.y * 128, n0 = blockIdx.x * 128;
  const int wm = (wave >> 1) * 64, wn = (wave & 1) * 64;
  const int l15 = lane & 15, lkb = lane >> 4;

  f32x4 acc[4][4] = {};

  auto stage = [&](int bsel, int k0) {
    #pragma unroll
    for (int it = 0; it < 2; ++it) {
      int c = it * 256 + tid;
      int row = c & 127, kb = c >> 7;
      int ar = m0 + row; ar = ar < M ? ar : M - 1;
      const __hip_bfloat16* ga = A + (size_t)ar * lda + (k0 + kb * 8);
      LOAD_LDS16(ga, &SA[bsel][it * 256 + wave * 64]);
      int br = n0 + row; br = br < Brows ? br : Brows - 1;
      const __hip_bfloat16* gb = Bw + (size_t)br * K + (k0 + kb * 8);
      LOAD_LDS16(gb, &SB[bsel][it * 256 + wave * 64]);
    }
  };

  const int nk = K >> 5;
  stage(0, 0);
  __syncthreads();
  int buf = 0;
  for (int kt = 0; kt < nk; ++kt) {
    if (kt + 1 < nk) stage(buf ^ 1, (kt + 1) * 32);
    bf16x8 af[4], bq[4];
    #pragma unroll
    for (int f = 0; f < 4; ++f) {
      af[f] = SA[buf][lkb * 128 + wm + f * 16 + l15];
      bq[f] = SB[buf][lkb * 128 + wn + f * 16 + l15];
    }
    #pragma unroll
    for (int i = 0; i < 4; ++i)
      #pragma unroll
      for (int j = 0; j < 4; ++j)
        acc[i][j] = __builtin_amdgcn_mfma_f32_16x16x32_bf16(af[i], bq[j], acc[i][j], 0, 0, 0);
    __syncthreads();
    buf ^= 1;
  }

  // C/D layout: col = lane&15, row = (lane>>4)*4 + reg
  #pragma unroll
  for (int i = 0; i < 4; ++i) {
    int r0 = m0 + wm + i * 16 + (lkb << 2);
    #pragma unroll
    for (int j = 0; j < 4; ++j) {
      int col = n0 + wn + j * 16 + l15;
      if (col >= N) continue;
      #pragma unroll
      for (int r = 0; r < 4; ++r) {
        int row = r0 + r;
        if (row >= M) continue;
        float v = acc[i][j][r];
        if (EPI >= 1) v += bias[col];
        if (EPI == 2) v *= aux[(size_t)row * N + col];
        if (EPI == 3) v = softplusf(v);
        if (EPI == 4) v *= aux[(size_t)(row % L_) * N + col];
        if (OF32) Cf[(size_t)row * N + col] = v;
        if (OBF)  Cb[(size_t)row * N + col] = __float2bfloat16(v);
      }
    }
  }
}

// ---------------------------------------------------------------------------
// Depthwise conv(k=4) + bias + silu, both directions; 4 channels per thread.
__global__ __launch_bounds__(256) void conv_silu(
    const __hip_bfloat16* __restrict__ xz, const float* __restrict__ w,
    const float* __restrict__ cb, __hip_bfloat16* __restrict__ xcbf)
{
  int t = blockIdx.x * 256 + threadIdx.x;     // 4 channels each
  int c4 = (t & (DI_ / 4 - 1)) * 4;
  int bl = t >> 8;
  int l = bl % L_;
  int b = bl / L_;
  const __hip_bfloat16* base = xz + (size_t)b * L_ * (2 * DI_) + c4;
  float xr[7][4];
  #pragma unroll
  for (int j = 0; j < 7; ++j) {
    int gl = l + j - 3;
    if (gl >= 0 && gl < L_) {
      u16x4 v = *(const u16x4*)(base + (size_t)gl * (2 * DI_));
      #pragma unroll
      for (int q = 0; q < 4; ++q) { unsigned int u = (unsigned int)v[q] << 16; xr[j][q] = __builtin_bit_cast(float, u); }
    } else {
      #pragma unroll
      for (int q = 0; q < 4; ++q) xr[j][q] = 0.f;
    }
  }
  __hip_bfloat16 of[4], ob[4];
  #pragma unroll
  for (int q = 0; q < 4; ++q) {
    int c = c4 + q;
    float w0 = w[c * 4], w1 = w[c * 4 + 1], w2 = w[c * 4 + 2], w3 = w[c * 4 + 3];
    float bias = cb[c];
    float sf = fmaf(w0, xr[0][q], fmaf(w1, xr[1][q], fmaf(w2, xr[2][q], fmaf(w3, xr[3][q], bias))));
    float sb = fmaf(w0, xr[6][q], fmaf(w1, xr[5][q], fmaf(w2, xr[4][q], fmaf(w3, xr[3][q], bias))));
    of[q] = __float2bfloat16(siluf(sf));
    ob[q] = __float2bfloat16(siluf(sb));
  }
  size_t o = (size_t)bl * DI_ + c4;
  *(u16x4*)(xcbf + o)         = *(u16x4*)of;
  *(u16x4*)(xcbf + LBDI_ + o) = *(u16x4*)ob;
}

// ---------------------------------------------------------------------------
// Selective scan v2: one thread per (dir,b,d,s); 16-lane shuffle reduce for y.
// y overwrites dt in place (readers of dt[row,d] are the same wave; load
// precedes store in wave program order).
__global__ __launch_bounds__(256) void scan_v2(
    float* __restrict__ dt, const __hip_bfloat16* __restrict__ xcbf,
    const float* __restrict__ xd,
    const float* __restrict__ A_log, const float* __restrict__ Dv)
{
  int tid = blockIdx.x * 256 + threadIdx.x;   // 524288 threads
  int s   = tid & 15;
  int seq = tid >> 4;
  int d   = seq & (DI_ - 1);
  int b   = (seq >> 10) & (B_ - 1);
  int dir = seq >> 14;
  float* dty = dt + (size_t)dir * LBDI_;
  const __hip_bfloat16* xc = xcbf + (size_t)dir * LBDI_;
  const float* xdp = xd + (size_t)dir * LB_ * 64;

  float A  = -__expf(A_log[d * 16 + s]);
  float Dd = Dv[d];
  float h  = 0.f;

  for (int step = 0; step < L_; ++step) {
    int l = dir ? (L_ - 1 - step) : step;
    size_t row = (size_t)b * L_ + l;
    float dtv = dty[row * DI_ + d];
    float xcv = __bfloat162float(xc[row * DI_ + d]);
    const float* r = xdp + row * 64;
    float Bv = r[32 + s], Cv = r[48 + s];
    h = fmaf(__expf(dtv * A), h, (dtv * xcv) * Bv);
    float p = h * Cv;
    p += __shfl_xor(p, 1); p += __shfl_xor(p, 2);
    p += __shfl_xor(p, 4); p += __shfl_xor(p, 8);
    if (s == 0) dty[row * DI_ + d] = fmaf(xcv, Dd, p);
  }
}

// yz = (y_f + y_b) * silu(z) -> bf16, 4 elems per thread
__global__ __launch_bounds__(256) void combine_yz(
    const float* __restrict__ y, const __hip_bfloat16* __restrict__ xz,
    __hip_bfloat16* __restrict__ yz)
{
  int t = blockIdx.x * 256 + threadIdx.x;
  int c4 = (t & (DI_ / 4 - 1)) * 4;
  int rowi = t >> 8;
  size_t o = (size_t)rowi * DI_ + c4;
  f32x4 yf = *(const f32x4*)(y + o);
  f32x4 yb = *(const f32x4*)(y + LBDI_ + o);
  u16x4 zv = *(const u16x4*)(xz + (size_t)rowi * (2 * DI_) + DI_ + c4);
  __hip_bfloat16 out[4];
  #pragma unroll
  for (int q = 0; q < 4; ++q) {
    unsigned int u = (unsigned int)zv[q] << 16;
    float z = __builtin_bit_cast(float, u);
    out[q] = __float2bfloat16((yf[q] + yb[q]) * siluf(z));
  }
  *(u16x4*)(yz + o) = *(u16x4*)out;
}

// ---------------------------------------------------------------------------
// tanh-LayerNorm over (L, D) per batch.
__global__ __launch_bounds__(256) void ln_partial(const float* __restrict__ x,
                                                  float* __restrict__ partials)
{
  int b = blockIdx.y, ch = blockIdx.x;
  const float* xb = x + (size_t)b * (L_ * DM_);
  int lo = ch * 12160, hi = lo + 12160;
  float s = 0.f, s2 = 0.f;
  for (int i = lo + threadIdx.x; i < hi; i += 256) {
    float t = tanhf(xb[i]);
    s += t; s2 = fmaf(t, t, s2);
  }
  #pragma unroll
  for (int off = 32; off > 0; off >>= 1) { s += __shfl_down(s, off); s2 += __shfl_down(s2, off); }
  __shared__ float rs[4], rs2[4];
  int wid = threadIdx.x >> 6, lane = threadIdx.x & 63;
  if (lane == 0) { rs[wid] = s; rs2[wid] = s2; }
  __syncthreads();
  if (threadIdx.x == 0) {
    partials[(b * 8 + ch) * 2 + 0] = rs[0] + rs[1] + rs[2] + rs[3];
    partials[(b * 8 + ch) * 2 + 1] = rs2[0] + rs2[1] + rs2[2] + rs2[3];
  }
}

__global__ __launch_bounds__(256) void ln_final(const float* __restrict__ x,
    const float* __restrict__ partials,
    const float* __restrict__ nw, const float* __restrict__ nb,
    float* __restrict__ out)
{
  int b = blockIdx.y, ch = blockIdx.x;
  float S = 0.f, S2 = 0.f;
  #pragma unroll
  for (int i = 0; i < 8; ++i) { S += partials[(b * 8 + i) * 2 + 0]; S2 += partials[(b * 8 + i) * 2 + 1]; }
  const float inv = 1.f / (float)(L_ * DM_);
  float mu = S * inv;
  float var = S2 * inv - mu * mu;
  float r = rsqrtf(var + 1e-5f);
  const float* xb = x + (size_t)b * (L_ * DM_);
  float* ob = out + (size_t)b * (L_ * DM_);
  int lo = ch * 12160, hi = lo + 12160;
  for (int i = lo + threadIdx.x; i < hi; i += 256) {
    float t = tanhf(xb[i]);
    ob[i] = fmaf((t - mu) * r, nw[i], nb[i]);
  }
}

// ---------------------------------------------------------------------------
extern "C" void kernel_launch(void* const* d_in, const int* in_sizes, int n_in,
                              void* d_out, int out_size, void* d_ws, size_t ws_size,
                              hipStream_t stream)
{
  const float* x            = (const float*)d_in[0];
  const void*  pc_mask      = d_in[1];
  const float* in_resize_w  = (const float*)d_in[2];
  const float* in_resize_b  = (const float*)d_in[3];
  const float* in_reset_w   = (const float*)d_in[4];
  const float* in_reset_b   = (const float*)d_in[5];
  const float* out_resize_w = (const float*)d_in[6];
  const float* out_resize_b = (const float*)d_in[7];
  const float* out_reset_w  = (const float*)d_in[8];
  const float* out_reset_b  = (const float*)d_in[9];
  const float* in_proj_w    = (const float*)d_in[10];
  const float* conv_w       = (const float*)d_in[11];
  const float* conv_b       = (const float*)d_in[12];
  const float* x_proj_w     = (const float*)d_in[13];
  const float* dt_proj_w    = (const float*)d_in[14];
  const float* dt_proj_b    = (const float*)d_in[15];
  const float* A_log        = (const float*)d_in[16];
  const float* Dv           = (const float*)d_in[17];
  const float* out_proj_w   = (const float*)d_in[18];
  const float* norm_w       = (const float*)d_in[19];
  const float* norm_b       = (const float*)d_in[20];

  // ---- workspace layout (f32 region then bf16 region) ----
  float* W = (float*)d_ws;
  float* maskf    = W + 0;         // 190*192 = 36480
  float* b_inrs   = W + 36480;     // 192
  float* b_outrs  = W + 36672;     // 192
  float* xd       = W + 36864;     // 2*3040*64 = 389120
  float* dt       = W + 425984;    // 2*3040*1024 = 6225920
  float* partials = W + 6651904;   // 256
  __hip_bfloat16* BF = (__hip_bfloat16*)(W + 6652160);
  __hip_bfloat16* w_inrs  = BF + 0;         // 192*512
  __hip_bfloat16* w_inrt  = BF + 98304;     // 512*192
  __hip_bfloat16* w_inpj  = BF + 196608;    // 2048*512
  __hip_bfloat16* w_xpj   = BF + 1245184;   // 64*1024
  __hip_bfloat16* w_dtpj  = BF + 1310720;   // 1024*32
  __hip_bfloat16* w_outpj = BF + 1343488;   // 512*1024
  __hip_bfloat16* w_outrs = BF + 1867776;   // 192*512
  __hip_bfloat16* w_outrt = BF + 1966080;   // 512*192
  __hip_bfloat16* x_bf    = BF + 2064384;   // 3040*512
  __hip_bfloat16* h1_bf   = BF + 3620864;   // 3040*192
  __hip_bfloat16* h_bf    = BF + 4204544;   // 3040*512
  __hip_bfloat16* xz_bf   = BF + 5761024;   // 3040*2048
  __hip_bfloat16* xc_bf   = BF + 11986944;  // 2*3040*1024
  __hip_bfloat16* xd_bf   = BF + 18212864;  // 2*3040*64
  __hip_bfloat16* yz_bf   = BF + 18601984;  // 3040*1024
  __hip_bfloat16* o_pre   = BF + 21714944;  // 3040*512
  __hip_bfloat16* o2_bf   = BF + 23271424;  // 3040*192

  float* out_ln = (float*)d_out;
  float* out_o  = (float*)d_out + (size_t)LB_ * DM_;

  dim3 blk(256);

  mask_convert<<<1, blk, 0, stream>>>(pc_mask, maskf, in_resize_b, out_resize_b, b_inrs, b_outrs);

  CvtPack P; int off = 0;
  auto addseg = [&](int i, const float* s, __hip_bfloat16* dptr, int R, int C, int Rp, int Cp) {
    off += Rp * Cp;
    P.d[i] = CvtDesc{ s, dptr, R, C, Rp, Cp, off };
  };
  addseg(0, x,            x_bf,    3040, 512, 3040, 512);
  addseg(1, in_resize_w,  w_inrs,  190, 512, 192, 512);
  addseg(2, in_reset_w,   w_inrt,  512, 190, 512, 192);
  addseg(3, in_proj_w,    w_inpj,  2048, 512, 2048, 512);
  addseg(4, x_proj_w,     w_xpj,   64, 1024, 64, 1024);
  addseg(5, dt_proj_w,    w_dtpj,  1024, 32, 1024, 32);
  addseg(6, out_proj_w,   w_outpj, 512, 1024, 512, 1024);
  addseg(7, out_resize_w, w_outrs, 190, 512, 192, 512);
  addseg(8, out_reset_w,  w_outrt, 512, 190, 512, 192);
  P.total = off;
  cvt_all<<<dim3(2048), blk, 0, stream>>>(P);

  // h1 = x @ in_resize_w^T + b                       (m[0,0]==1: diag of eye)
  gemm_mfma<1,false,true><<<dim3(2,24), blk, 0, stream>>>(x_bf, 512, 3040, w_inrs, 192, b_inrs, nullptr, nullptr, h1_bf, LP_, 512);
  // h = (h1 @ in_reset_w^T + b) * x
  gemm_mfma<2,false,true><<<dim3(4,24), blk, 0, stream>>>(h1_bf, LP_, 3040, w_inrt, 512, in_reset_b, x, nullptr, h_bf, 512, LP_);
  // xz = h @ in_proj_w^T
  gemm_mfma<0,false,true><<<dim3(16,24), blk, 0, stream>>>(h_bf, 512, 3040, w_inpj, 2048, nullptr, nullptr, nullptr, xz_bf, 2048, 512);
  // conv + silu (both dirs)
  conv_silu<<<dim3(LBDI_/1024), blk, 0, stream>>>(xz_bf, conv_w, conv_b, xc_bf);
  // x_dbl = xc @ x_proj_w^T  (both dirs batched: M=6080)
  gemm_mfma<0,true,true><<<dim3(1,48), blk, 0, stream>>>(xc_bf, 1024, 6080, w_xpj, 64, nullptr, nullptr, xd, xd_bf, 64, 1024);
  // dt = softplus(x_dbl[:,:32] @ dt_proj_w^T + b)
  gemm_mfma<3,true,false><<<dim3(8,48), blk, 0, stream>>>(xd_bf, 64, 6080, w_dtpj, 1024, dt_proj_b, nullptr, dt, nullptr, 1024, 32);
  // selective scan (state-parallel, y in place over dt)
  scan_v2<<<dim3(2048), blk, 0, stream>>>(dt, xc_bf, xd, A_log, Dv);
  // yz = (y_f + y_b) * silu(z)
  combine_yz<<<dim3(LBDI_/1024), blk, 0, stream>>>(dt, xz_bf, yz_bf);
  // o_pre = yz @ out_proj_w^T
  gemm_mfma<0,false,true><<<dim3(4,24), blk, 0, stream>>>(yz_bf, 1024, 3040, w_outpj, 512, nullptr, nullptr, nullptr, o_pre, 512, 1024);
  // o2 = (o_pre @ out_resize_w^T + b) * mask[l,:]
  gemm_mfma<4,false,true><<<dim3(2,24), blk, 0, stream>>>(o_pre, 512, 3040, w_outrs, 192, b_outrs, maskf, nullptr, o2_bf, LP_, 512);
  // o = (o2 @ out_reset_w^T + b) * x  -> output 1
  gemm_mfma<2,true,false><<<dim3(4,24), blk, 0, stream>>>(o2_bf, LP_, 3040, w_outrt, 512, out_reset_b, x, out_o, nullptr, 512, LP_);
  // output 0: layernorm(tanh(x))
  dim3 lgrid(8, B_);
  ln_partial<<<lgrid, blk, 0, stream>>>(x, partials);
  ln_final<<<lgrid, blk, 0, stream>>>(x, partials, norm_w, norm_b, out_ln);
}